// Round 3
// baseline (2533.743 us; speedup 1.0000x reference)
//
#include <hip/hip_runtime.h>
#include <math.h>

typedef float fx4 __attribute__((ext_vector_type(4)));

#define NBLK 1024
#define TPB  256
#define MAXC 128

// ---- init: zero the control words (graph replays re-run this each call) ----
__global__ void bitsel_init_kernel(int* __restrict__ ctr, int* __restrict__ rdy, int B) {
    int t = threadIdx.x;
    if (t < B) { ctr[t] = 0; rdy[t] = 0; }
}

// ---- fused persistent pipelined kernel ----
// Stage s: reduce slice of batch s; closer block finishes stds+head for batch s;
// then quant slice of batch s-1 (L2-hot from previous stage).
__global__ __launch_bounds__(TPB, 4)
void bitsel_fused_kernel(const fx4* __restrict__ x,
                         const float* __restrict__ gf,
                         const float* __restrict__ bits_in,
                         const float* __restrict__ wbits_in,
                         const float* __restrict__ Wl,
                         const float* __restrict__ bl,
                         const float* __restrict__ a1,
                         const float* __restrict__ a2,
                         const float* __restrict__ a3,
                         float* __restrict__ out,      // full out buffer
                         fx4*   __restrict__ res,      // out + 2B, as float4
                         float* __restrict__ ws_part,  // [B][NBLK][2]
                         float* __restrict__ ws_as,    // [B][2] (a, s)
                         int*   __restrict__ ws_ctr,   // [B]
                         int*   __restrict__ ws_rdy,   // [B]
                         int B, int C, int n4 /*f4 per channel*/,
                         int bpc /*blocks per channel*/, int slice4,
                         size_t Ntot) {
    const int j   = blockIdx.x;
    const int tid = threadIdx.x;
    const int c   = j / bpc;       // channel handled by this block
    const int sub = j % bpc;
    const int nblk = gridDim.x;

    __shared__ float ssum[4], ssq[4];
    __shared__ float s_std[MAXC];
    __shared__ float s_as[2];
    __shared__ int   s_close;

    for (int s = 0; s <= B; ++s) {
        // ---------------- phase A: reduce my slice of batch s ----------------
        if (s < B) {
            const size_t base = (size_t)(s * C + c) * (size_t)n4 + (size_t)sub * slice4;
            float sum = 0.f, sq = 0.f;
            for (int i = tid; i < slice4; i += TPB) {
                fx4 v = x[base + i];
                sum += (v.x + v.y) + (v.z + v.w);
                sq  += v.x * v.x + v.y * v.y + v.z * v.z + v.w * v.w;
            }
            for (int off = 32; off > 0; off >>= 1) {
                sum += __shfl_down(sum, off);
                sq  += __shfl_down(sq,  off);
            }
            __syncthreads();  // protect shared reuse from previous stage
            const int wv = tid >> 6;
            if ((tid & 63) == 0) { ssum[wv] = sum; ssq[wv] = sq; }
            __syncthreads();
            if (tid == 0) {
                float S = ssum[0] + ssum[1] + ssum[2] + ssum[3];
                float Q = ssq[0] + ssq[1] + ssq[2] + ssq[3];
                __hip_atomic_store(&ws_part[(size_t)(s * nblk + j) * 2 + 0], S,
                                   __ATOMIC_RELAXED, __HIP_MEMORY_SCOPE_AGENT);
                __hip_atomic_store(&ws_part[(size_t)(s * nblk + j) * 2 + 1], Q,
                                   __ATOMIC_RELAXED, __HIP_MEMORY_SCOPE_AGENT);
                int n = __hip_atomic_fetch_add(&ws_ctr[s], 1,
                                               __ATOMIC_ACQ_REL, __HIP_MEMORY_SCOPE_AGENT);
                s_close = (n == nblk - 1) ? 1 : 0;
            }
            __syncthreads();
            if (s_close) {  // block-uniform: this block closes batch s
                if (tid < C) {
                    float S = 0.f, Q = 0.f;
                    for (int k = 0; k < bpc; ++k) {
                        const size_t idx = (size_t)(s * nblk + tid * bpc + k) * 2;
                        S += __hip_atomic_load(&ws_part[idx + 0],
                                               __ATOMIC_RELAXED, __HIP_MEMORY_SCOPE_AGENT);
                        Q += __hip_atomic_load(&ws_part[idx + 1],
                                               __ATOMIC_RELAXED, __HIP_MEMORY_SCOPE_AGENT);
                    }
                    const float N = (float)(n4 * 4);
                    float var = (Q - S * S / N) / (N - 1.f);
                    s_std[tid] = sqrtf(fmaxf(var, 0.f));
                }
                __syncthreads();
                if (tid == 0) {
                    const int D = C + 2;
                    float bt[3];
                    for (int k = 0; k < 3; ++k) {
                        float acc = gf[2 * s] * Wl[k * D] + gf[2 * s + 1] * Wl[k * D + 1];
                        for (int cc = 0; cc < C; ++cc) acc += s_std[cc] * Wl[k * D + 2 + cc];
                        bt[k] = acc + bl[k];
                    }
                    int flag = 0; float m = bt[0];
                    if (bt[1] > m) { m = bt[1]; flag = 1; }
                    if (bt[2] > m) { m = bt[2]; flag = 2; }
                    float e0 = expf(bt[0] - m), e1 = expf(bt[1] - m), e2 = expf(bt[2] - m);
                    float esum = e0 + e1 + e2;
                    float p1 = e0 / esum, p2 = e1 / esum, p3 = e2 / esum;
                    float bits_hard = (flag == 0) ? 4.f : (flag == 1) ? 6.f : 8.f;
                    float bits_soft = 4.f * p1 + 6.f * p2 + 8.f * p3;
                    float bits_out  = (bits_hard - bits_soft) + bits_soft;
                    float denom     = 4.f * p1 + 6.f * p2 + 8.f * p3;
                    // tiny outputs for batch s
                    out[2 * s]     = gf[2 * s];
                    out[2 * s + 1] = gf[2 * s + 1];
                    out[2 * B + Ntot + s]     = bits_in[s] + bits_out;
                    out[2 * B + Ntot + B + s] = wbits_in[s] + bits_out / denom;
                    // publish (a, scale) then ready flag
                    float alpha = (flag == 0) ? a1[0] : (flag == 1) ? a2[0] : a3[0];
                    float a = fabsf(alpha);
                    float sc = (exp2f(bits_hard - 1.f) - 1.f) / a;
                    __hip_atomic_store(&ws_as[s * 2 + 0], a,
                                       __ATOMIC_RELAXED, __HIP_MEMORY_SCOPE_AGENT);
                    __hip_atomic_store(&ws_as[s * 2 + 1], sc,
                                       __ATOMIC_RELAXED, __HIP_MEMORY_SCOPE_AGENT);
                    __hip_atomic_store(&ws_rdy[s], 1,
                                       __ATOMIC_RELEASE, __HIP_MEMORY_SCOPE_AGENT);
                }
                __syncthreads();
            }
        }
        // ---------------- phase B: quant my slice of batch s-1 ----------------
        if (s >= 1) {
            const int b = s - 1;
            if (tid == 0) {
                while (__hip_atomic_load(&ws_rdy[b], __ATOMIC_ACQUIRE,
                                         __HIP_MEMORY_SCOPE_AGENT) == 0) {
                    __builtin_amdgcn_s_sleep(1);
                }
                s_as[0] = __hip_atomic_load(&ws_as[b * 2 + 0],
                                            __ATOMIC_RELAXED, __HIP_MEMORY_SCOPE_AGENT);
                s_as[1] = __hip_atomic_load(&ws_as[b * 2 + 1],
                                            __ATOMIC_RELAXED, __HIP_MEMORY_SCOPE_AGENT);
            }
            __syncthreads();
            const float a  = s_as[0];
            const float sc = s_as[1];
            const size_t base = (size_t)(b * C + c) * (size_t)n4 + (size_t)sub * slice4;
            for (int i = tid; i < slice4; i += TPB) {
                fx4 v = x[base + i];
                fx4 r;
                r.x = rintf(fminf(fmaxf(v.x, -a), a) * sc) / sc;
                r.y = rintf(fminf(fmaxf(v.y, -a), a) * sc) / sc;
                r.z = rintf(fminf(fmaxf(v.z, -a), a) * sc) / sc;
                r.w = rintf(fminf(fmaxf(v.w, -a), a) * sc) / sc;
                __builtin_nontemporal_store(r, &res[base + i]);
            }
        }
    }
}

extern "C" void kernel_launch(void* const* d_in, const int* in_sizes, int n_in,
                              void* d_out, int out_size, void* d_ws, size_t ws_size,
                              hipStream_t stream) {
    const float* x     = (const float*)d_in[0];
    const float* gf    = (const float*)d_in[1];
    const float* bits  = (const float*)d_in[2];
    const float* wbits = (const float*)d_in[3];
    const float* Wl    = (const float*)d_in[4];
    const float* bl    = (const float*)d_in[5];
    const float* a1    = (const float*)d_in[6];
    const float* a2    = (const float*)d_in[7];
    const float* a3    = (const float*)d_in[8];
    float* out = (float*)d_out;

    const int B   = in_sizes[2];                 // 16
    const int C   = in_sizes[4] / 3 - 2;         // 64
    const int HWn = in_sizes[0] / (B * C);       // 65536 floats per channel
    const int n4  = HWn / 4;                     // 16384 float4 per channel
    const int bpc = NBLK / C;                    // 16 blocks per channel
    const int slice4 = n4 / bpc;                 // 1024 float4 per block-slice
    const size_t Ntot = (size_t)in_sizes[0];

    // ws layout
    float* ws_part = (float*)d_ws;               // B*NBLK*2 floats
    float* ws_as   = ws_part + (size_t)B * NBLK * 2;  // B*2 floats
    int*   ws_ctr  = (int*)(ws_as + (size_t)B * 2);   // B ints
    int*   ws_rdy  = ws_ctr + B;                      // B ints

    bitsel_init_kernel<<<1, 64, 0, stream>>>(ws_ctr, ws_rdy, B);

    bitsel_fused_kernel<<<NBLK, TPB, 0, stream>>>(
        (const fx4*)x, gf, bits, wbits, Wl, bl, a1, a2, a3,
        out, (fx4*)(out + 2 * B),
        ws_part, ws_as, ws_ctr, ws_rdy,
        B, C, n4, bpc, slice4, Ntot);
}

// Round 4
// 136.825 us; speedup vs baseline: 18.5181x; 18.5181x over previous
//
#include <hip/hip_runtime.h>
#include <math.h>

typedef float fx4 __attribute__((ext_vector_type(4)));
#define TPB 256

// Fused R(gR) + Q(gQ) kernel.
//   blocks [0, nQ)        : quantize group gQ (needs partials of gQ from a
//                           PREVIOUS launch; head recomputed per block)
//   blocks [nQ, nQ + nR)  : partial-reduce group gR (sum / sumsq quarters)
// Launch sequence (kernel boundaries provide all ordering):
//   R(0); [R(1)+Q(0)]; [R(2)+Q(1)]; [R(3)+Q(2)]; Q(3)
__global__ __launch_bounds__(TPB)
void bitsel_rq_kernel(const fx4* __restrict__ x,
                      const float* __restrict__ gf,
                      const float* __restrict__ bits_in,
                      const float* __restrict__ wbits_in,
                      const float* __restrict__ Wl,
                      const float* __restrict__ bl,
                      const float* __restrict__ a1,
                      const float* __restrict__ a2,
                      const float* __restrict__ a3,
                      float* __restrict__ out,
                      fx4* __restrict__ res,
                      float* __restrict__ part,  // [NG][GB*C][ppc][2]
                      int gR, int gQ, int nQ,
                      int B, int C, int GB, int n4, int ppc,
                      size_t Ntot) {
    const int tid = threadIdx.x;

    if ((int)blockIdx.x >= nQ) {
        // ---------------- reduce a quarter-channel of group gR ----------------
        const int j  = (int)blockIdx.x - nQ;   // [0, GB*C*ppc)
        const int ch = j / ppc;                // channel-local within group
        const int pp = j % ppc;
        const int q4 = n4 / ppc;
        const size_t base = (size_t)(gR * GB * C + ch) * (size_t)n4 + (size_t)pp * q4;
        float sum = 0.f, sq = 0.f;
        for (int i = tid; i < q4; i += TPB) {
            fx4 v = x[base + i];
            sum += (v.x + v.y) + (v.z + v.w);
            sq  += v.x * v.x + v.y * v.y + v.z * v.z + v.w * v.w;
        }
        for (int off = 32; off > 0; off >>= 1) {
            sum += __shfl_down(sum, off);
            sq  += __shfl_down(sq,  off);
        }
        __shared__ float ssum[4], ssq[4];
        const int wv = tid >> 6;
        if ((tid & 63) == 0) { ssum[wv] = sum; ssq[wv] = sq; }
        __syncthreads();
        if (tid == 0) {
            float S = ssum[0] + ssum[1] + ssum[2] + ssum[3];
            float Q = ssq[0]  + ssq[1]  + ssq[2]  + ssq[3];
            const size_t idx = ((size_t)gR * (GB * C) + ch) * ppc + pp;
            part[idx * 2 + 0] = S;
            part[idx * 2 + 1] = Q;
        }
    } else {
        // ---------------- quantize a slice of group gQ ----------------
        const int k = (int)blockIdx.x;                 // [0, nQ)
        const int qblk4 = (GB * C * n4) / nQ;          // f4 per block (4096)
        const int bpb   = nQ / GB;                     // blocks per batch (256)
        const int bl_   = k / bpb;                     // batch-local
        const int b     = gQ * GB + bl_;

        __shared__ float s_std[128];
        __shared__ float s_as[2];

        // stds for this batch from partials (L2-hot, 2 KB)
        if (tid < C) {
            const size_t idx = ((size_t)gQ * (GB * C) + (size_t)bl_ * C + tid) * ppc;
            float S = 0.f, Qq = 0.f;
            for (int p = 0; p < ppc; ++p) {
                S  += part[(idx + p) * 2 + 0];
                Qq += part[(idx + p) * 2 + 1];
            }
            const float N = (float)n4 * 4.f;
            float var = (Qq - S * S / N) / (N - 1.f);
            s_std[tid] = sqrtf(fmaxf(var, 0.f));
        }
        __syncthreads();
        if (tid == 0) {
            const int D = C + 2;
            float bt[3];
            for (int kk = 0; kk < 3; ++kk) {
                float acc = gf[2 * b] * Wl[kk * D] + gf[2 * b + 1] * Wl[kk * D + 1];
                for (int cc = 0; cc < C; ++cc) acc += s_std[cc] * Wl[kk * D + 2 + cc];
                bt[kk] = acc + bl[kk];
            }
            int flag = 0; float m = bt[0];
            if (bt[1] > m) { m = bt[1]; flag = 1; }
            if (bt[2] > m) { m = bt[2]; flag = 2; }
            float e0 = expf(bt[0] - m), e1 = expf(bt[1] - m), e2 = expf(bt[2] - m);
            float esum = e0 + e1 + e2;
            float p1 = e0 / esum, p2 = e1 / esum, p3 = e2 / esum;
            float bits_hard = (flag == 0) ? 4.f : (flag == 1) ? 6.f : 8.f;
            float bits_soft = 4.f * p1 + 6.f * p2 + 8.f * p3;
            float bits_out  = (bits_hard - bits_soft) + bits_soft;  // STE fwd
            float denom     = 4.f * p1 + 6.f * p2 + 8.f * p3;
            float alpha = (flag == 0) ? a1[0] : (flag == 1) ? a2[0] : a3[0];
            float a  = fabsf(alpha);
            float sc = (exp2f(bits_hard - 1.f) - 1.f) / a;
            s_as[0] = a; s_as[1] = sc;
            if (k % bpb == 0) {  // one block per batch writes the tiny outputs
                out[2 * b]     = gf[2 * b];
                out[2 * b + 1] = gf[2 * b + 1];
                out[2 * B + Ntot + b]     = bits_in[b] + bits_out;
                out[2 * B + Ntot + B + b] = wbits_in[b] + bits_out / denom;
            }
        }
        __syncthreads();
        const float a  = s_as[0];
        const float sc = s_as[1];
        const size_t start = (size_t)(gQ * GB * C) * (size_t)n4 + (size_t)k * qblk4;
        for (int i = tid; i < qblk4; i += TPB) {
            fx4 v = x[start + i];
            fx4 r;
            r.x = rintf(fminf(fmaxf(v.x, -a), a) * sc) / sc;
            r.y = rintf(fminf(fmaxf(v.y, -a), a) * sc) / sc;
            r.z = rintf(fminf(fmaxf(v.z, -a), a) * sc) / sc;
            r.w = rintf(fminf(fmaxf(v.w, -a), a) * sc) / sc;
            __builtin_nontemporal_store(r, &res[start + i]);
        }
    }
}

extern "C" void kernel_launch(void* const* d_in, const int* in_sizes, int n_in,
                              void* d_out, int out_size, void* d_ws, size_t ws_size,
                              hipStream_t stream) {
    const float* x     = (const float*)d_in[0];
    const float* gf    = (const float*)d_in[1];
    const float* bits  = (const float*)d_in[2];
    const float* wbits = (const float*)d_in[3];
    const float* Wl    = (const float*)d_in[4];
    const float* bl    = (const float*)d_in[5];
    const float* a1    = (const float*)d_in[6];
    const float* a2    = (const float*)d_in[7];
    const float* a3    = (const float*)d_in[8];
    float* out = (float*)d_out;

    const int B   = in_sizes[2];                 // 16
    const int C   = in_sizes[4] / 3 - 2;         // 64
    const int HWn = in_sizes[0] / (B * C);       // 65536 floats per channel
    const int n4  = HWn / 4;                     // 16384 f4 per channel
    const int GB  = 4;                           // batches per group
    const int NG  = B / GB;                      // 4 groups
    const int ppc = 4;                           // partials per channel
    const int nR  = GB * C * ppc;                // 1024 reduce blocks
    const int nQ  = GB * C * n4 / 4096;          // 1024 quant blocks (4096 f4 ea)
    const size_t Ntot = (size_t)in_sizes[0];

    float* part = (float*)d_ws;                  // NG*GB*C*ppc*2 floats (32 KB)
    fx4* res = (fx4*)(out + 2 * B);

    // R(0)
    bitsel_rq_kernel<<<nR, TPB, 0, stream>>>(
        (const fx4*)x, gf, bits, wbits, Wl, bl, a1, a2, a3,
        out, res, part, 0, -1, 0, B, C, GB, n4, ppc, Ntot);
    // [R(g) + Q(g-1)]
    for (int g = 1; g < NG; ++g) {
        bitsel_rq_kernel<<<nQ + nR, TPB, 0, stream>>>(
            (const fx4*)x, gf, bits, wbits, Wl, bl, a1, a2, a3,
            out, res, part, g, g - 1, nQ, B, C, GB, n4, ppc, Ntot);
    }
    // Q(last)
    bitsel_rq_kernel<<<nQ, TPB, 0, stream>>>(
        (const fx4*)x, gf, bits, wbits, Wl, bl, a1, a2, a3,
        out, res, part, -1, NG - 1, nQ, B, C, GB, n4, ppc, Ntot);
}